// Round 7
// baseline (79.191 us; speedup 1.0000x reference)
//
#include <hip/hip_runtime.h>
#include <math.h>

#define HW    4096
#define NC    32
#define NB    8
#define TINV  10.0f            // 1/TEMP
#define RWIN  8                // window radius; missed sources need |of|>5.5
#define WDIM  24               // 8 + 2*RWIN
#define RCUT  2.5f             // rect cut; excluded normalized weight < 1e-7
#define LCAP  192              // list capacity (structural max 6 rows x 24 = 144)

// ws layout: params (float4 per b*HW) then xt (transposed x, [b][j][c])

__global__ __launch_bounds__(256) void prep_kernel(
    const float* __restrict__ x, const float* __restrict__ of,
    float4* __restrict__ params, float* __restrict__ xt)
{
    __shared__ float tile[32][257];
    int b  = blockIdx.x >> 4;
    int j0 = (blockIdx.x & 15) << 8;
    int t  = threadIdx.x;
    int j  = j0 + t;

    float oy = (float)(j >> 6) + of[(b * 2 + 0) * HW + j];
    float ox = (float)(j & 63) + of[(b * 2 + 1) * HW + j];

    // truncated denominators: omitted terms < e^-25 relative
    int cy0 = min(max((int)floorf(oy), 0), 63);
    int cx0 = min(max((int)floorf(ox), 0), 63);
    float Dy = 0.f, Dx = 0.f;
    #pragma unroll
    for (int d = -3; d <= 3; ++d) {
        int iy = cy0 + d, ix = cx0 + d;
        if ((unsigned)iy < 64u) Dy += __expf(-TINV * fabsf(oy - (float)iy));
        if ((unsigned)ix < 64u) Dx += __expf(-TINV * fabsf(ox - (float)ix));
    }
    params[(b << 12) + j] = make_float4(oy, ox, 1.f / Dy, 1.f / Dx);

    // LDS-tiled transpose x[b][c][j] -> xt[b][j][c]; both sides coalesced
    #pragma unroll
    for (int c = 0; c < NC; ++c)
        tile[c][t] = x[((b * NC + c) << 12) + j];
    __syncthreads();
    #pragma unroll
    for (int k = 0; k < NC; ++k) {
        int o  = k * 256 + t;
        int jj = o >> 5, c = o & 31;
        xt[((size_t)((b << 12) + j0 + jj)) * NC + c] = tile[c][jj];
    }
}

// fetch survivor idx (clamped) -> 4 float4 x-payload + params
#define FETCH(idx, Xb, Pb) do {                                         \
    int ic  = min((idx), cm1);                                          \
    int sel = ic >> 6;                                                  \
    int jv  = (sel == 0) ? vj0 : ((sel == 1) ? vj1 : vj2);              \
    int jj  = __builtin_amdgcn_readlane(jv, ic & 63);                   \
    const float4* xp = xb + jj * 8;                                     \
    Xb[0] = xp[0]; Xb[1] = xp[1]; Xb[2] = xp[2]; Xb[3] = xp[3];         \
    Pb = wp[wv][ic];                                                    \
} while (0)

#define COMPUTE(Xb, Pb, idx) do {                                       \
    float gy = __expf(-TINV * fabsf(Pb.x - iy)) * Pb.z;                 \
    float gx = __expf(-TINV * fabsf(Pb.y - ix)) * Pb.w;                 \
    float g  = ((idx) < cnt) ? gy * gx : 0.f;                           \
    acc[ 0] = fmaf(g, Xb[0].x, acc[ 0]);                                \
    acc[ 1] = fmaf(g, Xb[0].y, acc[ 1]);                                \
    acc[ 2] = fmaf(g, Xb[0].z, acc[ 2]);                                \
    acc[ 3] = fmaf(g, Xb[0].w, acc[ 3]);                                \
    acc[ 4] = fmaf(g, Xb[1].x, acc[ 4]);                                \
    acc[ 5] = fmaf(g, Xb[1].y, acc[ 5]);                                \
    acc[ 6] = fmaf(g, Xb[1].z, acc[ 6]);                                \
    acc[ 7] = fmaf(g, Xb[1].w, acc[ 7]);                                \
    acc[ 8] = fmaf(g, Xb[2].x, acc[ 8]);                                \
    acc[ 9] = fmaf(g, Xb[2].y, acc[ 9]);                                \
    acc[10] = fmaf(g, Xb[2].z, acc[10]);                                \
    acc[11] = fmaf(g, Xb[2].w, acc[11]);                                \
    acc[12] = fmaf(g, Xb[3].x, acc[12]);                                \
    acc[13] = fmaf(g, Xb[3].y, acc[13]);                                \
    acc[14] = fmaf(g, Xb[3].z, acc[14]);                                \
    acc[15] = fmaf(g, Xb[3].w, acc[15]);                                \
} while (0)

// grid: (64 tiles, 2 channel-halves, 8 batches); 16 channels per block
__global__ __launch_bounds__(256) void gather_kernel(
    const float4* __restrict__ params, const float4* __restrict__ xt4,
    float* __restrict__ out)
{
    __shared__ float  red[4 * 64 * 17];   // 17408 B
    __shared__ float4 wp[4][LCAP];        // 12288 B
    __shared__ int    sj[4][LCAP];        //  3072 B  -> 32 KB, 5 blocks/CU

    const int b    = blockIdx.z;
    const int h    = blockIdx.y;          // channel half
    const int tile = blockIdx.x;
    const int ty0  = (tile >> 3) << 3;
    const int tx0  = (tile & 7) << 3;

    const int tid  = threadIdx.x;
    const int lane = tid & 63;
    const int wv   = __builtin_amdgcn_readfirstlane(tid >> 6);

    const float iy = (float)(ty0 + (lane >> 3));
    const float ix = (float)(tx0 + (lane & 7));

    float acc[16];
    #pragma unroll
    for (int c = 0; c < 16; ++c) acc[c] = 0.f;

    const float4* pb = params + (b << 12);
    const float4* xb = xt4 + (size_t)(b << 12) * 8 + h * 4;  // 16 ch @ half h

    const int srow = lane >> 5;           // 2 window rows x 32 cols per round
    const int scol = lane & 31;

    // ---- Phase 1: screen all 3 rounds, append survivors to wave list ----
    int cnt = 0;
    #pragma unroll
    for (int r = 0; r < 3; ++r) {
        int ry = wv + srow * 4 + r * 8;   // all 24 rows over 4 waves
        int jy = ty0 - RWIN + ry;
        int jx = tx0 - RWIN + scol;
        bool valid = ((unsigned)jy < 64u) && ((unsigned)jx < 64u) && (scol < WDIM);
        int j = (jy << 6) + jx;
        float4 p = pb[valid ? j : 0];
        float cy = fminf(fmaxf(p.x, 0.f), 63.f);
        float cx = fminf(fmaxf(p.y, 0.f), 63.f);
        float dyr = fmaxf(fmaxf((float)ty0 - cy, cy - ((float)ty0 + 7.f)), 0.f);
        float dxr = fmaxf(fmaxf((float)tx0 - cx, cx - ((float)tx0 + 7.f)), 0.f);
        bool pred = valid && (dyr + dxr < RCUT);

        unsigned long long m = __ballot(pred);
        if (pred) {
            int pos = cnt + __builtin_amdgcn_mbcnt_hi((unsigned)(m >> 32),
                            __builtin_amdgcn_mbcnt_lo((unsigned)m, 0u));
            wp[wv][pos] = p;
            sj[wv][pos] = j;
        }
        cnt += __popcll(m);
    }

    // j-list into lane registers: addr path for survivor k = readlane (no LDS)
    int vj0 = sj[wv][lane];
    int vj1 = sj[wv][64 + lane];
    int vj2 = sj[wv][128 + lane];

    // ---- Phase 2: 4-slot pipelined processing (loads fly 2 batches ahead) ----
    if (cnt > 0) {
        const int cm1  = cnt - 1;
        const int cnt4 = (cnt + 3) & ~3;
        float4 X0[4], X1[4], X2[4], X3[4];
        float4 P0, P1, P2, P3;
        FETCH(0, X0, P0);
        FETCH(1, X1, P1);
        for (int k = 0; k < cnt4; k += 4) {
            FETCH(k + 2, X2, P2);
            FETCH(k + 3, X3, P3);
            COMPUTE(X0, P0, k + 0);
            COMPUTE(X1, P1, k + 1);
            if (k + 4 < cnt4) {
                FETCH(k + 4, X0, P0);
                FETCH(k + 5, X1, P1);
            }
            COMPUTE(X2, P2, k + 2);
            COMPUTE(X3, P3, k + 3);
        }
    }

    // ---- cross-wave reduction (stride 17 -> at most 2-way = free) ----
    float* myred = red + (wv * 64 + lane) * 17;
    #pragma unroll
    for (int c = 0; c < 16; ++c) myred[c] = acc[c];
    __syncthreads();

    int c   = tid >> 4;                   // 0..15
    int t16 = tid & 15;
    #pragma unroll
    for (int k = 0; k < 4; ++k) {
        int t = t16 + 16 * k;
        float s = red[(0 * 64 + t) * 17 + c]
                + red[(1 * 64 + t) * 17 + c]
                + red[(2 * 64 + t) * 17 + c]
                + red[(3 * 64 + t) * 17 + c];
        int ch = h * 16 + c;
        out[(((b << 5) + ch) << 12) + (ty0 + (t >> 3)) * 64 + (tx0 + (t & 7))] = s;
    }
}

extern "C" void kernel_launch(void* const* d_in, const int* in_sizes, int n_in,
                              void* d_out, int out_size, void* d_ws, size_t ws_size,
                              hipStream_t stream) {
    const float* x  = (const float*)d_in[0];   // [8,32,64,64]
    const float* of = (const float*)d_in[1];   // [8,2,64,64]
    float* out = (float*)d_out;                // [8,32,64,64] fp32

    float4* params = (float4*)d_ws;                                    // 512 KB
    float*  xt     = (float*)((char*)d_ws + NB * HW * sizeof(float4)); // 4 MB

    prep_kernel<<<dim3(NB * 16), dim3(256), 0, stream>>>(x, of, params, xt);
    gather_kernel<<<dim3(64, 2, NB), dim3(256), 0, stream>>>(params, (const float4*)xt, out);
}